// Round 6
// baseline (434.807 us; speedup 1.0000x reference)
//
#include <hip/hip_runtime.h>
#include <hip/hip_cooperative_groups.h>

namespace cg = cooperative_groups;

#define N_CLAUSES 50000
#define FEAT_DIM 64
#define EMBED_DIM 128
#define NUM_QUEUES 8
#define NUM_STEPS 2048
#define ENTROPY_COEF 0.1f

#define GRID_BLOCKS 400     // = NCHUNK(25) * NUM_QUEUES(8) * SGRP(2)
#define NB1 196             // ceil(50000/256) logits blocks
#define CHUNK 2048
#define NCHUNK 25
#define ILOOP 32            // i-iterations per phase-2 block (KPG=128)

typedef unsigned int v4u __attribute__((ext_vector_type(4)));
typedef unsigned int v2u __attribute__((ext_vector_type(2)));

// ---------------- workspace layout (float units) ----------------
#define WS_LOGITS 0                 // [8][50000]
#define WS_ROWMAX 400000            // [8] int-encoded max
#define WS_K2T    400008            // [128][8]
#define WS_CQ     401032            // [8]
#define WS_W1T    401040            // [128][64]
#define WS_FLAG   409232            // int: 1 = byte mask, 0 = int32 mask
#define WS_PART   409248            // [NCHUNK][NUM_STEPS] float4

struct Params {
  const float* fv; const float* W1; const float* b1; const float* W2;
  const float* b2; const float* keys; const float* rewards;
  const void* mask; const int* qi; const int* si;
  float* W1T; float* K2T; float* cq; int* flag; int* rowmax_i;
  float* logits; float4* part; float* out;
};

// order-preserving float<->int encode for atomicMax on signed int
__device__ inline int enc_f(float f) {
  int b = __float_as_int(f);
  return b >= 0 ? b : (b ^ 0x7FFFFFFF);
}
__device__ inline float dec_f(int k) {
  return __int_as_float(k >= 0 ? k : (k ^ 0x7FFFFFFF));
}

__global__ __launch_bounds__(256) void k_mega(Params p) {
  cg::grid_group grid = cg::this_grid();
  const int bid = blockIdx.x, t = threadIdx.x;
  __shared__ float sred[4][8];
  __shared__ float sv[4];

  // ================= phase 0: prep (blocks 0..3) =================
  if (bid == 0) {                      // W1T = W1^T
    for (int i = t; i < FEAT_DIM * EMBED_DIM; i += 256) {
      int j = i >> 6, f = i & 63;
      p.W1T[j * 64 + f] = p.W1[f * EMBED_DIM + j];
    }
  } else if (bid == 1) {               // K2T[j][q] = sum_e W2[j,e]*keys[q,e]
    for (int idx = t; idx < EMBED_DIM * NUM_QUEUES; idx += 256) {
      int j = idx >> 3, q = idx & 7;
      float a = 0.f;
      for (int e = 0; e < EMBED_DIM; ++e)
        a = fmaf(p.W2[j * EMBED_DIM + e], p.keys[q * EMBED_DIM + e], a);
      p.K2T[idx] = a;
    }
  } else if (bid == 2) {               // cq + rowmax init
    if (t < NUM_QUEUES) {
      float a = 0.f;
      for (int e = 0; e < EMBED_DIM; ++e)
        a = fmaf(p.b2[e], p.keys[t * EMBED_DIM + e], a);
      p.cq[t] = a;
      p.rowmax_i[t] = (int)0x80000000;  // INT_MIN
    }
  } else if (bid == 3) {               // mask dtype flag (self-contained)
    __shared__ int sfl;
    if (t == 0) sfl = 0;
    __syncthreads();
    const unsigned* mw = (const unsigned*)p.mask;
    bool fl = (mw[t] > 1u) | (mw[t + 256] > 1u) | (mw[t + 512] > 1u) | (mw[t + 768] > 1u);
    if (__any(fl) && (t & 63) == 0) atomicOr(&sfl, 1);
    __syncthreads();
    if (t == 0) *p.flag = sfl;
  }

  grid.sync();   // prep -> logits

  // ================= phase 1: logits + rowmax =================
  if (bid < NB1) {
    int n = bid * 256 + t;
    bool act = n < N_CLAUSES;
    int nn = act ? n : (N_CLAUSES - 1);
    float r[FEAT_DIM];
    const float4* fp = (const float4*)(p.fv + (size_t)nn * FEAT_DIM);
#pragma unroll
    for (int i = 0; i < FEAT_DIM / 4; ++i) {
      float4 v = fp[i];
      r[4 * i] = v.x; r[4 * i + 1] = v.y; r[4 * i + 2] = v.z; r[4 * i + 3] = v.w;
    }
    float acc[NUM_QUEUES];
#pragma unroll
    for (int q = 0; q < NUM_QUEUES; ++q) acc[q] = p.cq[q];
#pragma unroll 4
    for (int j = 0; j < EMBED_DIM; ++j) {
      const float* w = p.W1T + j * 64;   // wave-uniform -> scalar loads
      float t0 = 0.f, t1 = 0.f, t2 = 0.f, t3 = 0.f;
#pragma unroll
      for (int f = 0; f < FEAT_DIM; f += 4) {
        t0 = fmaf(r[f],     w[f],     t0);
        t1 = fmaf(r[f + 1], w[f + 1], t1);
        t2 = fmaf(r[f + 2], w[f + 2], t2);
        t3 = fmaf(r[f + 3], w[f + 3], t3);
      }
      float tt = fmaxf((t0 + t1) + (t2 + t3) + p.b1[j], 0.f);
      const float* k2 = p.K2T + j * 8;
#pragma unroll
      for (int q = 0; q < NUM_QUEUES; ++q) acc[q] = fmaf(tt, k2[q], acc[q]);
    }
    if (act) {
#pragma unroll
      for (int q = 0; q < NUM_QUEUES; ++q)
        p.logits[(size_t)q * N_CLAUSES + n] = acc[q];
    }
    // per-queue wave butterfly max -> LDS -> 8 atomics per block
    float red[NUM_QUEUES];
#pragma unroll
    for (int q = 0; q < NUM_QUEUES; ++q) {
      float m = acc[q];
#pragma unroll
      for (int o = 32; o > 0; o >>= 1) m = fmaxf(m, __shfl_xor(m, o, 64));
      red[q] = m;
    }
    if ((t & 63) == 0) {
      int w = t >> 6;
      sred[w][0] = red[0]; sred[w][1] = red[1]; sred[w][2] = red[2]; sred[w][3] = red[3];
      sred[w][4] = red[4]; sred[w][5] = red[5]; sred[w][6] = red[6]; sred[w][7] = red[7];
    }
    __syncthreads();
    if (t < NUM_QUEUES) {
      float m = fmaxf(fmaxf(sred[0][t], sred[1][t]), fmaxf(sred[2][t], sred[3][t]));
      atomicMax(&p.rowmax_i[t], enc_f(m));
    }
  }

  grid.sync();   // logits -> steps

  // ================= phase 2: queue-major masked-softmax =================
  {
    int chunk = bid % NCHUNK, rr = bid / NCHUNK;
    int q = rr & 7, g = rr >> 3;        // g in {0,1}
    int w = t >> 6;
    int base = chunk * CHUNK + 8 * t;
    bool act = base < N_CLAUSES;        // 8-aligned: all-or-none per thread
    float M = dec_f(p.rowmax_i[q]);
    float e[8], es[8];
#pragma unroll
    for (int j = 0; j < 8; ++j) { e[j] = 0.f; es[j] = 0.f; }
    if (act) {
      const float* lrow = p.logits + (size_t)q * N_CLAUSES + base;
      float4 l0 = *(const float4*)(lrow);
      float4 l1 = *(const float4*)(lrow + 4);
      float a[8] = {l0.x - M, l0.y - M, l0.z - M, l0.w - M,
                    l1.x - M, l1.y - M, l1.z - M, l1.w - M};
#pragma unroll
      for (int j = 0; j < 8; ++j) { e[j] = __expf(a[j]); es[j] = e[j] * a[j]; }
    }
    int k0 = g * 128 + w;
    int s0 = q + 8 * k0;                // s stride per i is 32
    float4* pout = p.part + (size_t)chunk * NUM_STEPS;
    if (*p.flag != 0) {
      // ---- byte mask path ----
      const unsigned char* mb = (const unsigned char*)p.mask + (size_t)s0 * N_CLAUSES + base;
#pragma unroll 2
      for (int i = 0; i < ILOOP; ++i) {
        float z = 0.f, s1 = 0.f, c = 0.f;
        if (act) {
          v2u m = __builtin_nontemporal_load((const v2u*)(mb + (size_t)32 * N_CLAUSES * i));
          unsigned mw2[2] = {m.x, m.y};
#pragma unroll
          for (int h = 0; h < 2; ++h) {
#pragma unroll
            for (int k = 0; k < 4; ++k) {
              float bb = ((mw2[h] >> (8 * k)) & 0xffu) ? 1.f : 0.f;
              int j = 4 * h + k;
              z = fmaf(bb, e[j], z);
              s1 = fmaf(bb, es[j], s1);
              c += bb;
            }
          }
        }
#pragma unroll
        for (int o = 32; o > 0; o >>= 1) {
          z += __shfl_xor(z, o, 64); s1 += __shfl_xor(s1, o, 64); c += __shfl_xor(c, o, 64);
        }
        if ((t & 63) == 0) pout[s0 + 32 * i] = make_float4(z, s1, c, 0.f);
      }
    } else {
      // ---- int32 mask path ----
      const int* mi = (const int*)p.mask + (size_t)s0 * N_CLAUSES + base;
#pragma unroll 2
      for (int i = 0; i < ILOOP; ++i) {
        float z = 0.f, s1 = 0.f, c = 0.f;
        if (act) {
          const int* pp = mi + (size_t)32 * N_CLAUSES * i;
          v4u m0 = __builtin_nontemporal_load((const v4u*)pp);
          v4u m1 = __builtin_nontemporal_load((const v4u*)(pp + 4));
          unsigned mv[8] = {m0.x, m0.y, m0.z, m0.w, m1.x, m1.y, m1.z, m1.w};
#pragma unroll
          for (int j = 0; j < 8; ++j) {
            float bb = mv[j] ? 1.f : 0.f;
            z = fmaf(bb, e[j], z);
            s1 = fmaf(bb, es[j], s1);
            c += bb;
          }
        }
#pragma unroll
        for (int o = 32; o > 0; o >>= 1) {
          z += __shfl_xor(z, o, 64); s1 += __shfl_xor(s1, o, 64); c += __shfl_xor(c, o, 64);
        }
        if ((t & 63) == 0) pout[s0 + 32 * i] = make_float4(z, s1, c, 0.f);
      }
    }
  }

  grid.sync();   // steps -> reduce

  // ================= phase 3: reduce + loss + sum (block 0) =================
  if (bid == 0) {
    float lsum = 0.f;
#pragma unroll 2
    for (int k = 0; k < 8; ++k) {
      int s = (k << 8) | t;
      float z = 0.f, s1 = 0.f, c = 0.f;
      for (int e2 = 0; e2 < NCHUNK; ++e2) {
        float4 pp = p.part[(size_t)e2 * NUM_STEPS + s];   // lanes contiguous in s
        z += pp.x; s1 += pp.y; c += pp.z;
      }
      int q = p.qi[s];
      float M = dec_f(p.rowmax_i[q]);
      float ssel = p.logits[(size_t)q * N_CLAUSES + p.si[s]];
      float logZ = logf(z);
      float ce = logZ - (ssel - M);          // = -log_softmax[sel]
      float me = (s1 / z - logZ) / logf(c);  // normalized minus-entropy
      lsum += p.rewards[s] * ce + ENTROPY_COEF * me;
    }
#pragma unroll
    for (int o = 32; o > 0; o >>= 1) lsum += __shfl_xor(lsum, o, 64);
    if ((t & 63) == 0) sv[t >> 6] = lsum;
    __syncthreads();
    if (t == 0) p.out[0] = sv[0] + sv[1] + sv[2] + sv[3];
  }
}

extern "C" void kernel_launch(void* const* d_in, const int* in_sizes, int n_in,
                              void* d_out, int out_size, void* d_ws, size_t ws_size,
                              hipStream_t stream) {
  float* ws = (float*)d_ws;
  Params prm;
  prm.fv      = (const float*)d_in[0];
  prm.W1      = (const float*)d_in[1];
  prm.b1      = (const float*)d_in[2];
  prm.W2      = (const float*)d_in[3];
  prm.b2      = (const float*)d_in[4];
  prm.keys    = (const float*)d_in[5];
  prm.rewards = (const float*)d_in[6];
  prm.mask    = d_in[7];
  prm.qi      = (const int*)d_in[8];
  prm.si      = (const int*)d_in[9];
  prm.W1T     = ws + WS_W1T;
  prm.K2T     = ws + WS_K2T;
  prm.cq      = ws + WS_CQ;
  prm.flag    = (int*)(ws + WS_FLAG);
  prm.rowmax_i= (int*)(ws + WS_ROWMAX);
  prm.logits  = ws + WS_LOGITS;
  prm.part    = (float4*)(ws + WS_PART);
  prm.out     = (float*)d_out;

  void* args[] = {(void*)&prm};
  hipLaunchCooperativeKernel((void*)k_mega, dim3(GRID_BLOCKS), dim3(256),
                             args, 0, stream);
}

// Round 7
// 198.796 us; speedup vs baseline: 2.1872x; 2.1872x over previous
//
#include <hip/hip_runtime.h>

#define N_CLAUSES 50000
#define FEAT_DIM 64
#define EMBED_DIM 128
#define NUM_QUEUES 8
#define NUM_STEPS 2048
#define ENTROPY_COEF 0.1f

typedef unsigned int v4u __attribute__((ext_vector_type(4)));

// ---------------- workspace layout (float units) ----------------
#define WS_LOGITS 0                 // [8][50000]
#define WS_ROWMAX 400000            // [8] int-encoded max
#define WS_K2T    400008            // [128][8]
#define WS_CQ     401032            // [8]
#define WS_W1T    401040            // [128][64]
#define WS_FLAG   409232            // int: 1 = byte mask, 0 = int32 mask
#define WS_LOSS   409248            // [2048]

// order-preserving float<->int encode for atomicMax on signed int
__device__ inline int enc_f(float f) {
  int b = __float_as_int(f);
  return b >= 0 ? b : (b ^ 0x7FFFFFFF);
}
__device__ inline float dec_f(int k) {
  return __int_as_float(k >= 0 ? k : (k ^ 0x7FFFFFFF));
}

__global__ __launch_bounds__(1024) void k_prep(const float* __restrict__ W1,
    const float* __restrict__ b2, const float* __restrict__ W2,
    const float* __restrict__ keys, const unsigned int* __restrict__ maskw,
    float* __restrict__ W1T, float* __restrict__ K2T, float* __restrict__ cq,
    int* __restrict__ flag, int* __restrict__ rowmax_i) {
  int tid = threadIdx.x;
  __shared__ int sflag;
  if (tid == 0) sflag = 0;
  __syncthreads();
  if (maskw[tid] > 1u) atomicOr(&sflag, 1);
  {
    int q = tid >> 7, j = tid & 127;
    float a = 0.f;
    for (int e = 0; e < EMBED_DIM; ++e)
      a = fmaf(W2[j * EMBED_DIM + e], keys[q * EMBED_DIM + e], a);
    K2T[j * 8 + q] = a;
  }
  if (tid < NUM_QUEUES) {
    float a = 0.f;
    for (int e = 0; e < EMBED_DIM; ++e)
      a = fmaf(b2[e], keys[tid * EMBED_DIM + e], a);
    cq[tid] = a;
    rowmax_i[tid] = (int)0x80000000;   // INT_MIN
  }
  for (int i = tid; i < FEAT_DIM * EMBED_DIM; i += 1024) {
    int j = i >> 6, f = i & 63;
    W1T[j * 64 + f] = W1[f * EMBED_DIM + j];
  }
  __syncthreads();
  if (tid == 0) *flag = sflag;
}

// logits[q][n] = relu(fv[n]@W1 + b1) . K2[q] + cq[q]; fused per-queue row-max
// (wave butterfly -> LDS -> atomicMax on int-encoded float; order-independent).
__global__ __launch_bounds__(256) void k_logits(const float* __restrict__ fv,
    const float* __restrict__ b1, const float* __restrict__ W1T,
    const float* __restrict__ K2T, const float* __restrict__ cq,
    float* __restrict__ logits, int* __restrict__ rowmax_i) {
  int t = threadIdx.x;
  int n = blockIdx.x * 256 + t;
  bool act = n < N_CLAUSES;
  int nn = act ? n : (N_CLAUSES - 1);
  float r[FEAT_DIM];
  const float4* fp = (const float4*)(fv + (size_t)nn * FEAT_DIM);
#pragma unroll
  for (int i = 0; i < FEAT_DIM / 4; ++i) {
    float4 v = fp[i];
    r[4 * i] = v.x; r[4 * i + 1] = v.y; r[4 * i + 2] = v.z; r[4 * i + 3] = v.w;
  }
  float acc[NUM_QUEUES];
#pragma unroll
  for (int q = 0; q < NUM_QUEUES; ++q) acc[q] = cq[q];
#pragma unroll 4
  for (int j = 0; j < EMBED_DIM; ++j) {
    const float* w = W1T + j * 64;   // wave-uniform -> scalar loads
    float t0 = 0.f, t1 = 0.f, t2 = 0.f, t3 = 0.f;
#pragma unroll
    for (int f = 0; f < FEAT_DIM; f += 4) {
      t0 = fmaf(r[f],     w[f],     t0);
      t1 = fmaf(r[f + 1], w[f + 1], t1);
      t2 = fmaf(r[f + 2], w[f + 2], t2);
      t3 = fmaf(r[f + 3], w[f + 3], t3);
    }
    float tt = fmaxf((t0 + t1) + (t2 + t3) + b1[j], 0.f);
    const float* k2 = K2T + j * 8;
#pragma unroll
    for (int q = 0; q < NUM_QUEUES; ++q) acc[q] = fmaf(tt, k2[q], acc[q]);
  }
  if (act) {
#pragma unroll
    for (int q = 0; q < NUM_QUEUES; ++q)
      logits[(size_t)q * N_CLAUSES + n] = acc[q];
  }
  __shared__ float sred[4][8];
  float red[NUM_QUEUES];
#pragma unroll
  for (int q = 0; q < NUM_QUEUES; ++q) {
    float m = acc[q];   // inactive lanes: duplicate of clause 49999 (harmless for max)
#pragma unroll
    for (int o = 32; o > 0; o >>= 1) m = fmaxf(m, __shfl_xor(m, o, 64));
    red[q] = m;
  }
  if ((t & 63) == 0) {
    int w = t >> 6;
#pragma unroll
    for (int q = 0; q < NUM_QUEUES; ++q) sred[w][q] = red[q];
  }
  __syncthreads();
  if (t < NUM_QUEUES) {
    float m = fmaxf(fmaxf(sred[0][t], sred[1][t]), fmaxf(sred[2][t], sred[3][t]));
    atomicMax(&rowmax_i[t], enc_f(m));
  }
}

// One block per step. Mask row is CONTIGUOUS per block (nontemporal stream);
// logits row comes from L2 (8 rows = 1.6 MB per XCD, heavily reused);
// exp recomputed inline (VALU was 95% idle). ~61 independent loads/thread -> MLP.
__global__ __launch_bounds__(256) void k_step(const float* __restrict__ logits,
    const int* __restrict__ rowmax_i, const void* __restrict__ maskv,
    const int* __restrict__ flag, const float* __restrict__ rewards,
    const int* __restrict__ qi, const int* __restrict__ si,
    float* __restrict__ loss) {
  int s = blockIdx.x, t = threadIdx.x;
  int q = qi[s];
  float M = dec_f(rowmax_i[q]);
  const float* lrow = logits + (size_t)q * N_CLAUSES;
  float z = 0.f, s1 = 0.f, c = 0.f;

  if (*flag != 0) {
    // ---- byte mask: 3125 uint4 per row; 12 uniform iters + tail (t < 53) ----
    const v4u* mrow = (const v4u*)((const unsigned char*)maskv + (size_t)s * N_CLAUSES);
    auto body = [&](int ti) {
      v4u m = __builtin_nontemporal_load(mrow + ti);
      const float4* lp = (const float4*)(lrow + ti * 16);
      unsigned mw[4] = {m.x, m.y, m.z, m.w};
#pragma unroll
      for (int g = 0; g < 4; ++g) {
        float4 l = lp[g];
        float ls[4] = {l.x, l.y, l.z, l.w};
#pragma unroll
        for (int k = 0; k < 4; ++k) {
          float bb = ((mw[g] >> (8 * k)) & 0xffu) ? 1.f : 0.f;
          float a = ls[k] - M;
          float e = __expf(a);       // a <= 0 always
          z = fmaf(bb, e, z);
          s1 = fmaf(bb, e * a, s1);
          c += bb;
        }
      }
    };
#pragma unroll 2
    for (int i = 0; i < 12; ++i) body(i * 256 + t);
    if (t < 3125 - 12 * 256) body(12 * 256 + t);
  } else {
    // ---- int32 mask: 12500 uint4 (4 clauses each); 48 uniform iters + tail ----
    const v4u* mrow = (const v4u*)((const int*)maskv + (size_t)s * N_CLAUSES);
    auto body = [&](int ti) {
      v4u m = __builtin_nontemporal_load(mrow + ti);
      float4 l = *(const float4*)(lrow + ti * 4);
      unsigned mv[4] = {m.x, m.y, m.z, m.w};
      float ls[4] = {l.x, l.y, l.z, l.w};
#pragma unroll
      for (int k = 0; k < 4; ++k) {
        float bb = mv[k] ? 1.f : 0.f;
        float a = ls[k] - M;
        float e = __expf(a);
        z = fmaf(bb, e, z);
        s1 = fmaf(bb, e * a, s1);
        c += bb;
      }
    };
#pragma unroll 4
    for (int i = 0; i < 48; ++i) body(i * 256 + t);
    if (t < 12500 - 48 * 256) body(48 * 256 + t);
  }

#pragma unroll
  for (int o = 32; o > 0; o >>= 1) {
    z += __shfl_xor(z, o, 64);
    s1 += __shfl_xor(s1, o, 64);
    c += __shfl_xor(c, o, 64);
  }
  __shared__ float sZ[4], sS[4], sC[4];
  int w = t >> 6;
  if ((t & 63) == 0) { sZ[w] = z; sS[w] = s1; sC[w] = c; }
  __syncthreads();
  if (t == 0) {
    float Zt = sZ[0] + sZ[1] + sZ[2] + sZ[3];
    float St = sS[0] + sS[1] + sS[2] + sS[3];
    float Ct = sC[0] + sC[1] + sC[2] + sC[3];
    float ssel = lrow[si[s]];
    float logZ = logf(Zt);
    float ce = logZ - (ssel - M);          // = -log_softmax[sel]
    float me = (St / Zt - logZ) / logf(Ct);// normalized minus-entropy
    loss[s] = rewards[s] * ce + ENTROPY_COEF * me;
  }
}

__global__ __launch_bounds__(256) void k_sum(const float* __restrict__ loss,
                                             float* __restrict__ out) {
  int tid = threadIdx.x;
  float v = 0.f;
  for (int i = tid; i < NUM_STEPS; i += 256) v += loss[i];
#pragma unroll
  for (int o = 32; o > 0; o >>= 1) v += __shfl_xor(v, o, 64);
  __shared__ float sv[4];
  if ((tid & 63) == 0) sv[tid >> 6] = v;
  __syncthreads();
  if (tid == 0) out[0] = sv[0] + sv[1] + sv[2] + sv[3];
}

extern "C" void kernel_launch(void* const* d_in, const int* in_sizes, int n_in,
                              void* d_out, int out_size, void* d_ws, size_t ws_size,
                              hipStream_t stream) {
  const float* fv      = (const float*)d_in[0];
  const float* W1      = (const float*)d_in[1];
  const float* b1      = (const float*)d_in[2];
  const float* W2      = (const float*)d_in[3];
  const float* b2      = (const float*)d_in[4];
  const float* keys    = (const float*)d_in[5];
  const float* rewards = (const float*)d_in[6];
  const void*  mask    = d_in[7];
  const int*   queue_i = (const int*)d_in[8];
  const int*   sel_i   = (const int*)d_in[9];
  float* out = (float*)d_out;
  float* ws  = (float*)d_ws;

  float* logits   = ws + WS_LOGITS;
  int*   rowmax_i = (int*)(ws + WS_ROWMAX);
  float* K2T      = ws + WS_K2T;
  float* cq       = ws + WS_CQ;
  float* W1T      = ws + WS_W1T;
  int*   flag     = (int*)(ws + WS_FLAG);
  float* loss     = ws + WS_LOSS;

  hipLaunchKernelGGL(k_prep, dim3(1), dim3(1024), 0, stream,
                     W1, b2, W2, keys, (const unsigned int*)mask, W1T, K2T, cq, flag, rowmax_i);
  hipLaunchKernelGGL(k_logits, dim3((N_CLAUSES + 255) / 256), dim3(256), 0, stream,
                     fv, b1, W1T, K2T, cq, logits, rowmax_i);
  hipLaunchKernelGGL(k_step, dim3(NUM_STEPS), dim3(256), 0, stream,
                     logits, rowmax_i, mask, flag, rewards, queue_i, sel_i, loss);
  hipLaunchKernelGGL(k_sum, dim3(1), dim3(256), 0, stream, loss, out);
}

// Round 8
// 195.360 us; speedup vs baseline: 2.2257x; 1.0176x over previous
//
#include <hip/hip_runtime.h>

#define N_CLAUSES 50000
#define FEAT_DIM 64
#define EMBED_DIM 128
#define NUM_QUEUES 8
#define NUM_STEPS 2048
#define ENTROPY_COEF 0.1f

typedef unsigned int v4u __attribute__((ext_vector_type(4)));

// ---------------- workspace layout (float units) ----------------
#define WS_LOGITS 0                 // [8][50000]
#define WS_ROWMAX 400000            // [8] int-encoded max
#define WS_K2T    400008            // [128][8]
#define WS_CQ     401032            // [8]
#define WS_W1T    401040            // [128][64]
#define WS_LOSS   409232            // [2048]

// order-preserving float<->int encode for atomicMax on signed int
__device__ inline int enc_f(float f) {
  int b = __float_as_int(f);
  return b >= 0 ? b : (b ^ 0x7FFFFFFF);
}
__device__ inline float dec_f(int k) {
  return __int_as_float(k >= 0 ? k : (k ^ 0x7FFFFFFF));
}

__global__ __launch_bounds__(1024) void k_prep(const float* __restrict__ W1,
    const float* __restrict__ b2, const float* __restrict__ W2,
    const float* __restrict__ keys, float* __restrict__ W1T,
    float* __restrict__ K2T, float* __restrict__ cq, int* __restrict__ rowmax_i) {
  int tid = threadIdx.x;
  {
    int q = tid >> 7, j = tid & 127;
    float a = 0.f;
    for (int e = 0; e < EMBED_DIM; ++e)
      a = fmaf(W2[j * EMBED_DIM + e], keys[q * EMBED_DIM + e], a);
    K2T[j * 8 + q] = a;
  }
  if (tid < NUM_QUEUES) {
    float a = 0.f;
    for (int e = 0; e < EMBED_DIM; ++e)
      a = fmaf(b2[e], keys[tid * EMBED_DIM + e], a);
    cq[tid] = a;
    rowmax_i[tid] = (int)0x80000000;   // INT_MIN
  }
  for (int i = tid; i < FEAT_DIM * EMBED_DIM; i += 1024) {
    int j = i >> 6, f = i & 63;
    W1T[j * 64 + f] = W1[f * EMBED_DIM + j];
  }
}

// logits[q][n] = relu(fv[n]@W1 + b1) . K2[q] + cq[q]; fused per-queue row-max
// (wave butterfly -> LDS -> 8 atomicMax per block on int-encoded float).
__global__ __launch_bounds__(256) void k_logits(const float* __restrict__ fv,
    const float* __restrict__ b1, const float* __restrict__ W1T,
    const float* __restrict__ K2T, const float* __restrict__ cq,
    float* __restrict__ logits, int* __restrict__ rowmax_i) {
  int t = threadIdx.x;
  int n = blockIdx.x * 256 + t;
  bool act = n < N_CLAUSES;
  int nn = act ? n : (N_CLAUSES - 1);
  float r[FEAT_DIM];
  const float4* fp = (const float4*)(fv + (size_t)nn * FEAT_DIM);
#pragma unroll
  for (int i = 0; i < FEAT_DIM / 4; ++i) {
    float4 v = fp[i];
    r[4 * i] = v.x; r[4 * i + 1] = v.y; r[4 * i + 2] = v.z; r[4 * i + 3] = v.w;
  }
  float acc[NUM_QUEUES];
#pragma unroll
  for (int q = 0; q < NUM_QUEUES; ++q) acc[q] = cq[q];
#pragma unroll 4
  for (int j = 0; j < EMBED_DIM; ++j) {
    const float* w = W1T + j * 64;   // wave-uniform -> scalar loads
    float t0 = 0.f, t1 = 0.f, t2 = 0.f, t3 = 0.f;
#pragma unroll
    for (int f = 0; f < FEAT_DIM; f += 4) {
      t0 = fmaf(r[f],     w[f],     t0);
      t1 = fmaf(r[f + 1], w[f + 1], t1);
      t2 = fmaf(r[f + 2], w[f + 2], t2);
      t3 = fmaf(r[f + 3], w[f + 3], t3);
    }
    float tt = fmaxf((t0 + t1) + (t2 + t3) + b1[j], 0.f);
    const float* k2 = K2T + j * 8;
#pragma unroll
    for (int q = 0; q < NUM_QUEUES; ++q) acc[q] = fmaf(tt, k2[q], acc[q]);
  }
  if (act) {
#pragma unroll
    for (int q = 0; q < NUM_QUEUES; ++q)
      logits[(size_t)q * N_CLAUSES + n] = acc[q];
  }
  __shared__ float sred[4][8];
  float red[NUM_QUEUES];
#pragma unroll
  for (int q = 0; q < NUM_QUEUES; ++q) {
    float m = acc[q];   // inactive lanes duplicate clause 49999 (harmless for max)
#pragma unroll
    for (int o = 32; o > 0; o >>= 1) m = fmaxf(m, __shfl_xor(m, o, 64));
    red[q] = m;
  }
  if ((t & 63) == 0) {
    int w = t >> 6;
#pragma unroll
    for (int q = 0; q < NUM_QUEUES; ++q) sred[w][q] = red[q];
  }
  __syncthreads();
  if (t < NUM_QUEUES) {
    float m = fmaxf(fmaxf(sred[0][t], sred[1][t]), fmaxf(sred[2][t], sred[3][t]));
    atomicMax(&rowmax_i[t], enc_f(m));
  }
}

// One block per step. Thread handles 4 CONSECUTIVE clauses per iter:
// byte path = u32 mask (4 B/lane) + float4 logits (16 B/lane) -- both coalesced.
// Mask nontemporal (single-use stream); logits temporal (reused 256x per XCD;
// q = s%8 and round-robin block->XCD puts one 200 KB row per XCD L2).
__global__ __launch_bounds__(256) void k_step(const float* __restrict__ logits,
    const int* __restrict__ rowmax_i, const void* __restrict__ maskv,
    const float* __restrict__ rewards, const int* __restrict__ qi,
    const int* __restrict__ si, float* __restrict__ loss) {
  int s = blockIdx.x, t = threadIdx.x;
  // self-detect mask dtype from first 1024 words (L2-hot; per-wave __any,
  // byte-mask detection probability per wave = 1 - 0.343^256 ~= 1)
  const unsigned* mw0 = (const unsigned*)maskv;
  bool bytemask = __any((mw0[t] > 1u) | (mw0[t + 256] > 1u) |
                        (mw0[t + 512] > 1u) | (mw0[t + 768] > 1u));
  int q = qi[s];
  float M = dec_f(rowmax_i[q]);
  const float4* lrow4 = (const float4*)(logits + (size_t)q * N_CLAUSES);
  const float* lrow = logits + (size_t)q * N_CLAUSES;
  float z = 0.f, s1 = 0.f, c = 0.f;

  if (bytemask) {
    // 12500 u32 words (4 clauses each): 48 uniform iters + tail (t < 212)
    const unsigned* mrow = (const unsigned*)((const unsigned char*)maskv + (size_t)s * N_CLAUSES);
    auto body = [&](int idx) {
      unsigned m = __builtin_nontemporal_load(mrow + idx);
      float4 l = lrow4[idx];
      float b0 = (m & 0x000000ffu) ? 1.f : 0.f;
      float b1 = (m & 0x0000ff00u) ? 1.f : 0.f;
      float b2 = (m & 0x00ff0000u) ? 1.f : 0.f;
      float b3 = (m & 0xff000000u) ? 1.f : 0.f;
      float a0 = l.x - M, a1 = l.y - M, a2 = l.z - M, a3 = l.w - M;
      float e0 = __expf(a0), e1 = __expf(a1), e2 = __expf(a2), e3 = __expf(a3);
      z  = fmaf(b0, e0, z);       z  = fmaf(b1, e1, z);
      z  = fmaf(b2, e2, z);       z  = fmaf(b3, e3, z);
      s1 = fmaf(b0, e0 * a0, s1); s1 = fmaf(b1, e1 * a1, s1);
      s1 = fmaf(b2, e2 * a2, s1); s1 = fmaf(b3, e3 * a3, s1);
      c += (b0 + b1) + (b2 + b3);
    };
#pragma unroll 4
    for (int i = 0; i < 48; ++i) body(i * 256 + t);
    if (t < 212) body(12288 + t);
  } else {
    // 12500 uint4 (4 int32 clauses each): same structure
    const v4u* mrow = (const v4u*)((const int*)maskv + (size_t)s * N_CLAUSES);
    auto body = [&](int idx) {
      v4u m = __builtin_nontemporal_load(mrow + idx);
      float4 l = lrow4[idx];
      float b0 = m.x ? 1.f : 0.f;
      float b1 = m.y ? 1.f : 0.f;
      float b2 = m.z ? 1.f : 0.f;
      float b3 = m.w ? 1.f : 0.f;
      float a0 = l.x - M, a1 = l.y - M, a2 = l.z - M, a3 = l.w - M;
      float e0 = __expf(a0), e1 = __expf(a1), e2 = __expf(a2), e3 = __expf(a3);
      z  = fmaf(b0, e0, z);       z  = fmaf(b1, e1, z);
      z  = fmaf(b2, e2, z);       z  = fmaf(b3, e3, z);
      s1 = fmaf(b0, e0 * a0, s1); s1 = fmaf(b1, e1 * a1, s1);
      s1 = fmaf(b2, e2 * a2, s1); s1 = fmaf(b3, e3 * a3, s1);
      c += (b0 + b1) + (b2 + b3);
    };
#pragma unroll 4
    for (int i = 0; i < 48; ++i) body(i * 256 + t);
    if (t < 212) body(12288 + t);
  }

#pragma unroll
  for (int o = 32; o > 0; o >>= 1) {
    z += __shfl_xor(z, o, 64);
    s1 += __shfl_xor(s1, o, 64);
    c += __shfl_xor(c, o, 64);
  }
  __shared__ float sZ[4], sS[4], sC[4];
  int w = t >> 6;
  if ((t & 63) == 0) { sZ[w] = z; sS[w] = s1; sC[w] = c; }
  __syncthreads();
  if (t == 0) {
    float Zt = sZ[0] + sZ[1] + sZ[2] + sZ[3];
    float St = sS[0] + sS[1] + sS[2] + sS[3];
    float Ct = sC[0] + sC[1] + sC[2] + sC[3];
    float ssel = lrow[si[s]];
    float logZ = logf(Zt);
    float ce = logZ - (ssel - M);            // = -log_softmax[sel]
    float me = (St / Zt - logZ) / logf(Ct);  // normalized minus-entropy
    loss[s] = rewards[s] * ce + ENTROPY_COEF * me;
  }
}

__global__ __launch_bounds__(256) void k_sum(const float* __restrict__ loss,
                                             float* __restrict__ out) {
  int tid = threadIdx.x;
  float v = 0.f;
  for (int i = tid; i < NUM_STEPS; i += 256) v += loss[i];
#pragma unroll
  for (int o = 32; o > 0; o >>= 1) v += __shfl_xor(v, o, 64);
  __shared__ float sv[4];
  if ((tid & 63) == 0) sv[tid >> 6] = v;
  __syncthreads();
  if (tid == 0) out[0] = sv[0] + sv[1] + sv[2] + sv[3];
}

extern "C" void kernel_launch(void* const* d_in, const int* in_sizes, int n_in,
                              void* d_out, int out_size, void* d_ws, size_t ws_size,
                              hipStream_t stream) {
  const float* fv      = (const float*)d_in[0];
  const float* W1      = (const float*)d_in[1];
  const float* b1      = (const float*)d_in[2];
  const float* W2      = (const float*)d_in[3];
  const float* b2      = (const float*)d_in[4];
  const float* keys    = (const float*)d_in[5];
  const float* rewards = (const float*)d_in[6];
  const void*  mask    = d_in[7];
  const int*   queue_i = (const int*)d_in[8];
  const int*   sel_i   = (const int*)d_in[9];
  float* out = (float*)d_out;
  float* ws  = (float*)d_ws;

  float* logits   = ws + WS_LOGITS;
  int*   rowmax_i = (int*)(ws + WS_ROWMAX);
  float* K2T      = ws + WS_K2T;
  float* cq       = ws + WS_CQ;
  float* W1T      = ws + WS_W1T;
  float* loss     = ws + WS_LOSS;

  hipLaunchKernelGGL(k_prep, dim3(1), dim3(1024), 0, stream,
                     W1, b2, W2, keys, W1T, K2T, cq, rowmax_i);
  hipLaunchKernelGGL(k_logits, dim3((N_CLAUSES + 255) / 256), dim3(256), 0, stream,
                     fv, b1, W1T, K2T, cq, logits, rowmax_i);
  hipLaunchKernelGGL(k_step, dim3(NUM_STEPS), dim3(256), 0, stream,
                     logits, rowmax_i, mask, rewards, queue_i, sel_i, loss);
  hipLaunchKernelGGL(k_sum, dim3(1), dim3(256), 0, stream, loss, out);
}